// Round 5
// baseline (293.108 us; speedup 1.0000x reference)
//
#include <hip/hip_runtime.h>
#include <hip/hip_bf16.h>
#include <stdint.h>

#define NTEST 4096
#define NTRAIN 16384
#define DIM 128
#define KEXP 256   // A'=[hi,hi] x B'=[hi,lo]  ->  dot = hi_t.(hi_r+lo_r) = hi_t.x_r

typedef __attribute__((ext_vector_type(8))) short short8;
typedef __attribute__((ext_vector_type(4))) float float4v;

static __device__ __forceinline__ unsigned short f32_to_bf16_rne(float f) {
    union { float f; uint32_t u; } v; v.f = f;
    uint32_t u = v.u;
    uint32_t r = u + 0x7FFFu + ((u >> 16) & 1u);
    return (unsigned short)(r >> 16);
}
static __device__ __forceinline__ float bf16_bits_to_f32(unsigned short h) {
    union { uint32_t u; float f; } v; v.u = ((uint32_t)h) << 16;
    return v.f;
}

// ---- Kernel 1: per-column partial sums for std (coalesced) + zero out ----
__global__ void col_stats_partial(const float* __restrict__ train,
                                  float* __restrict__ psum, float* __restrict__ psumsq,
                                  float* __restrict__ out) {
    int b = blockIdx.x;       // 128 blocks x 128 rows each
    int t = threadIdx.x;      // 256
    if (b < 16) out[b * 256 + t] = 0.f;   // zero output (re-poisoned each call)
    int col = t & 127;
    int rh = t >> 7;          // 0/1
    float s = 0.f, ss = 0.f;
    int row0 = b * 128;
    for (int r = rh; r < 128; r += 2) {
        float x = train[(size_t)(row0 + r) * DIM + col];
        s += x; ss += x * x;
    }
    __shared__ float sh_s[256], sh_ss[256];
    sh_s[t] = s; sh_ss[t] = ss;
    __syncthreads();
    if (rh == 0) {
        psum[b * DIM + col]   = sh_s[col] + sh_s[col + 128];
        psumsq[b * DIM + col] = sh_ss[col] + sh_ss[col + 128];
    }
}

// ---- Kernel 2: bandwidth + Z scalars (256 threads, 2-way split) ----
__global__ void bandwidth_kernel(const float* __restrict__ psum, const float* __restrict__ psumsq,
                                 float* __restrict__ inv_bw, float* __restrict__ scalars) {
    int t = threadIdx.x;      // 256
    int c = t & 127;
    int h = t >> 7;
    float s = 0.f, ss = 0.f;
    for (int b = h * 64; b < h * 64 + 64; ++b) { s += psum[b * DIM + c]; ss += psumsq[b * DIM + c]; }
    __shared__ float S[256], SS[256], sh[128];
    S[t] = s; SS[t] = ss;
    __syncthreads();
    if (h == 0) {
        s = S[c] + S[c + 128]; ss = SS[c] + SS[c + 128];
        float n = (float)NTRAIN;
        float var = (ss - s * s / n) / (n - 1.0f);
        float sd = fmaxf(sqrtf(var), 0.01f);
        float bw = 1.06f * sd * expf(-logf(n) / (float)(4 + DIM));
        bw = fminf(bw, 0.49f);
        inv_bw[c] = 1.0f / bw;
        sh[c] = logf(bw);
    }
    __syncthreads();
    for (int off = 64; off > 0; off >>= 1) {
        if (t < off) sh[t] += sh[t + off];
        __syncthreads();
    }
    if (t == 0) {
        float Z = 0.5f * (float)DIM * logf(2.0f * 3.14159265358979323846f) + sh[0] + logf((float)NTRAIN);
        scalars[0] = -0.5f / Z;   // term = exp(scale*sq - 1)
    }
}

// ---- Kernel 3: train rows only: scale, hi/lo bf16 split, row norms ----
__global__ void expand_train(const float* __restrict__ train, const float* __restrict__ inv_bw,
                             unsigned short* __restrict__ Be, float* __restrict__ rnorm) {
    int t = threadIdx.x;
    int r = blockIdx.x * 2 + (t >> 7);    // 0..NTRAIN-1
    int k = t & 127;
    float x = train[(size_t)r * DIM + k] * inv_bw[k];
    unsigned short hi = f32_to_bf16_rne(x);
    float lo_f = x - bf16_bits_to_f32(hi);
    unsigned short lo = f32_to_bf16_rne(lo_f);
    size_t base = (size_t)r * KEXP;
    Be[base + k] = hi; Be[base + DIM + k] = lo;
    float nv = x * x;   // norms use exact fp32 x
    #pragma unroll
    for (int off = 32; off > 0; off >>= 1) nv += __shfl_xor(nv, off, 64);
    __shared__ float sh[4];
    if ((t & 63) == 0) sh[t >> 6] = nv;
    __syncthreads();
    if (k == 0) rnorm[r] = sh[(t >> 6)] + sh[(t >> 6) + 1];
}

// ---- Kernel 4: barrier-free streamed GEMM ----
// Block: 64 test-rows. A built in-kernel from test (scale+bf16), LDS-resident
// over K=256, XOR-swizzled (conflict-free). B fragments loaded straight to
// VGPRs from global (no LDS, no barriers in the stream loop). 8 n-tiles of 128.
__global__ __launch_bounds__(256, 3) void kde_main(
    const float* __restrict__ test, const unsigned short* __restrict__ Be,
    const float* __restrict__ inv_bw,
    const float* __restrict__ rnorm,
    const float* __restrict__ scalars, float* __restrict__ out) {

    __shared__ __align__(16) unsigned short As[64 * 256];   // 32 KB, swizzled chunks
    __shared__ float tn_lds[64];

    const int t = threadIdx.x;
    const int m0 = blockIdx.x * 64;      // 64 m-blocks (x fastest: co-dispatched share grp)
    const int grp = blockIdx.y;          // 16 n-groups of 8 tiles
    const int wave = t >> 6;
    const int lane = t & 63;
    const int wm = wave >> 1, wn = wave & 1;
    const int lrow = lane & 15;
    const int q = lane >> 4;

    // ---- prologue: build A (hi,hi) in LDS + tnorm, from raw test rows ----
    {
        int half = t >> 5;               // 0..7: row within group of 8
        int cl = t & 31;                 // col chunk of 4 floats
        float4 inv4 = *(const float4*)(inv_bw + cl * 4);
        #pragma unroll
        for (int rr = 0; rr < 8; ++rr) {
            int row = rr * 8 + half;
            float4 v = *(const float4*)(test + (size_t)(m0 + row) * DIM + cl * 4);
            v.x *= inv4.x; v.y *= inv4.y; v.z *= inv4.z; v.w *= inv4.w;
            ushort4 hv;
            hv.x = f32_to_bf16_rne(v.x); hv.y = f32_to_bf16_rne(v.y);
            hv.z = f32_to_bf16_rne(v.z); hv.w = f32_to_bf16_rne(v.w);
            int p = cl >> 1;                 // K-chunk 0..15 (copy 1), p+16 (copy 2)
            int sub = (cl & 1) * 4;
            int rx = row & 7;
            *(ushort4*)(As + row * 256 + ((p ^ rx) << 3) + sub) = hv;
            *(ushort4*)(As + row * 256 + (((p + 16) ^ rx) << 3) + sub) = hv;
            float nv = v.x * v.x + v.y * v.y + v.z * v.z + v.w * v.w;
            #pragma unroll
            for (int off = 1; off < 32; off <<= 1) nv += __shfl_xor(nv, off, 64);
            if (cl == 0) tn_lds[row] = nv;
        }
    }
    const float scale = scalars[0];

    int abase[2], arx[2];
    #pragma unroll
    for (int tm = 0; tm < 2; ++tm) {
        int row = wm * 32 + tm * 16 + lrow;
        abase[tm] = row * 256;
        arx[tm] = row & 7;
    }

    __syncthreads();   // the only barrier: A + tnorm visible

    float tnv[2][4];
    #pragma unroll
    for (int tm = 0; tm < 2; ++tm)
        #pragma unroll
        for (int r = 0; r < 4; ++r)
            tnv[tm][r] = tn_lds[wm * 32 + tm * 16 + q * 4 + r];

    const unsigned short* bp[4];
    {
        size_t b0 = ((size_t)(grp * 8) * 128 + wn * 64 + lrow) * KEXP;
        #pragma unroll
        for (int tn = 0; tn < 4; ++tn) bp[tn] = Be + b0 + (size_t)tn * 16 * KEXP;
    }

    float rs[2][4] = {{0.f,0.f,0.f,0.f},{0.f,0.f,0.f,0.f}};

    for (int j = 0; j < 8; ++j) {
        float rnv[4];
        int n0j = (grp * 8 + j) * 128 + wn * 64 + lrow;
        #pragma unroll
        for (int tn = 0; tn < 4; ++tn) rnv[tn] = rnorm[n0j + tn * 16];

        float4v acc[2][4];
        #pragma unroll
        for (int i = 0; i < 2; ++i)
            #pragma unroll
            for (int jj = 0; jj < 4; ++jj) { float4v z = {0.f,0.f,0.f,0.f}; acc[i][jj] = z; }

        #pragma unroll
        for (int kt = 0; kt < 8; ++kt) {
            short8 bfv[4], af[2];
            #pragma unroll
            for (int tn = 0; tn < 4; ++tn)
                bfv[tn] = *(const short8*)(bp[tn] + kt * 32 + q * 8);
            #pragma unroll
            for (int tm = 0; tm < 2; ++tm)
                af[tm] = *(const short8*)(As + abase[tm] + ((((kt << 2) | q) ^ arx[tm]) << 3));
            #pragma unroll
            for (int tm = 0; tm < 2; ++tm)
                #pragma unroll
                for (int tn = 0; tn < 4; ++tn)
                    acc[tm][tn] = __builtin_amdgcn_mfma_f32_16x16x32_bf16(af[tm], bfv[tn], acc[tm][tn], 0, 0, 0);
        }

        #pragma unroll
        for (int tm = 0; tm < 2; ++tm) {
            #pragma unroll
            for (int r = 0; r < 4; ++r) {
                float c0 = tnv[tm][r];
                float sum = 0.f;
                #pragma unroll
                for (int tn = 0; tn < 4; ++tn) {
                    float sq = fmaxf(c0 + rnv[tn] - 2.0f * acc[tm][tn][r], 0.0f);
                    sum += __expf(fmaf(scale, sq, -1.0f));
                }
                rs[tm][r] += sum;
            }
        }
        #pragma unroll
        for (int tn = 0; tn < 4; ++tn) bp[tn] += 128 * KEXP;
    }

    // ---- final: 16-lane reduce + one atomic per (tm,r) ----
    #pragma unroll
    for (int tm = 0; tm < 2; ++tm) {
        #pragma unroll
        for (int r = 0; r < 4; ++r) {
            float v = rs[tm][r];
            #pragma unroll
            for (int off = 1; off < 16; off <<= 1)
                v += __shfl_xor(v, off, 64);
            if (lrow == 0)
                atomicAdd(&out[m0 + wm * 32 + tm * 16 + q * 4 + r], v);
        }
    }
}

extern "C" void kernel_launch(void* const* d_in, const int* in_sizes, int n_in,
                              void* d_out, int out_size, void* d_ws, size_t ws_size,
                              hipStream_t stream) {
    const float* test  = (const float*)d_in[0];
    const float* train = (const float*)d_in[1];
    float* out = (float*)d_out;

    char* ws = (char*)d_ws;
    unsigned short* Be = (unsigned short*)ws;            // 16384*256*2 = 8,388,608 B
    float* fws    = (float*)(ws + 8388608);
    float* rnorm  = fws;                 // 16384
    float* psum   = rnorm + NTRAIN;      // 16384
    float* psumsq = psum + 16384;        // 16384
    float* inv_bw = psumsq + 16384;      // 128
    float* scalars = inv_bw + 128;       // 8

    hipLaunchKernelGGL(col_stats_partial, dim3(128), dim3(256), 0, stream, train, psum, psumsq, out);
    hipLaunchKernelGGL(bandwidth_kernel, dim3(1), dim3(256), 0, stream, psum, psumsq, inv_bw, scalars);
    hipLaunchKernelGGL(expand_train, dim3(NTRAIN / 2), dim3(256), 0, stream,
                       train, inv_bw, Be, rnorm);
    hipLaunchKernelGGL(kde_main, dim3(NTEST / 64, 16), dim3(256), 0, stream,
                       test, Be, inv_bw, rnorm, scalars, out);
}

// Round 6
// 140.869 us; speedup vs baseline: 2.0807x; 2.0807x over previous
//
#include <hip/hip_runtime.h>
#include <hip/hip_bf16.h>
#include <stdint.h>

#define NTEST 4096
#define NTRAIN 16384
#define DIM 128
#define KEXP 128   // pure hi.hi bf16 (norms exact fp32; split-correction dropped)

typedef __attribute__((ext_vector_type(8))) short short8;
typedef __attribute__((ext_vector_type(16))) float float16v;

static __device__ __forceinline__ unsigned short f32_to_bf16_rne(float f) {
    union { float f; uint32_t u; } v; v.f = f;
    uint32_t u = v.u;
    uint32_t r = u + 0x7FFFu + ((u >> 16) & 1u);
    return (unsigned short)(r >> 16);
}

// ---- Kernel 1: per-column partial sums for std (coalesced) + zero out ----
__global__ void col_stats_partial(const float* __restrict__ train,
                                  float* __restrict__ psum, float* __restrict__ psumsq,
                                  float* __restrict__ out) {
    int b = blockIdx.x;       // 128 blocks x 128 rows each
    int t = threadIdx.x;      // 256
    if (b < 16) out[b * 256 + t] = 0.f;   // zero output (re-poisoned each call)
    int col = t & 127;
    int rh = t >> 7;          // 0/1
    float s = 0.f, ss = 0.f;
    int row0 = b * 128;
    for (int r = rh; r < 128; r += 2) {
        float x = train[(size_t)(row0 + r) * DIM + col];
        s += x; ss += x * x;
    }
    __shared__ float sh_s[256], sh_ss[256];
    sh_s[t] = s; sh_ss[t] = ss;
    __syncthreads();
    if (rh == 0) {
        psum[b * DIM + col]   = sh_s[col] + sh_s[col + 128];
        psumsq[b * DIM + col] = sh_ss[col] + sh_ss[col + 128];
    }
}

// ---- Kernel 2: bandwidth + Z scalars ----
__global__ void bandwidth_kernel(const float* __restrict__ psum, const float* __restrict__ psumsq,
                                 float* __restrict__ inv_bw, float* __restrict__ scalars) {
    int t = threadIdx.x;      // 256
    int c = t & 127;
    int h = t >> 7;
    float s = 0.f, ss = 0.f;
    for (int b = h * 64; b < h * 64 + 64; ++b) { s += psum[b * DIM + c]; ss += psumsq[b * DIM + c]; }
    __shared__ float S[256], SS[256], sh[128];
    S[t] = s; SS[t] = ss;
    __syncthreads();
    if (h == 0) {
        s = S[c] + S[c + 128]; ss = SS[c] + SS[c + 128];
        float n = (float)NTRAIN;
        float var = (ss - s * s / n) / (n - 1.0f);
        float sd = fmaxf(sqrtf(var), 0.01f);
        float bw = 1.06f * sd * expf(-logf(n) / (float)(4 + DIM));
        bw = fminf(bw, 0.49f);
        inv_bw[c] = 1.0f / bw;
        sh[c] = logf(bw);
    }
    __syncthreads();
    for (int off = 64; off > 0; off >>= 1) {
        if (t < off) sh[t] += sh[t + off];
        __syncthreads();
    }
    if (t == 0) {
        float Z = 0.5f * (float)DIM * logf(2.0f * 3.14159265358979323846f) + sh[0] + logf((float)NTRAIN);
        scalars[0] = -0.5f / Z;   // term = exp(scale*sq - 1)
    }
}

// ---- Kernel 3: train rows: scale, bf16 hi, exact row norms ----
__global__ void expand_train(const float* __restrict__ train, const float* __restrict__ inv_bw,
                             unsigned short* __restrict__ Be, float* __restrict__ rnorm) {
    int t = threadIdx.x;
    int r = blockIdx.x * 2 + (t >> 7);    // 0..NTRAIN-1
    int k = t & 127;
    float x = train[(size_t)r * DIM + k] * inv_bw[k];
    Be[(size_t)r * KEXP + k] = f32_to_bf16_rne(x);
    float nv = x * x;   // exact fp32 norm
    #pragma unroll
    for (int off = 32; off > 0; off >>= 1) nv += __shfl_xor(nv, off, 64);
    __shared__ float sh[4];
    if ((t & 63) == 0) sh[t >> 6] = nv;
    __syncthreads();
    if (k == 0) rnorm[r] = sh[(t >> 6)] + sh[(t >> 6) + 1];
}

// ---- Kernel 4: 128x128-tile GEMM (32x32x16 MFMA), B double-buffered+swizzled ----
__global__ __launch_bounds__(256, 2) void kde_main(
    const float* __restrict__ test, const unsigned short* __restrict__ Be,
    const float* __restrict__ inv_bw, const float* __restrict__ rnorm,
    const float* __restrict__ scalars, float* __restrict__ out) {

    __shared__ __align__(16) unsigned short As[128 * 128];      // 32 KB: 128 rows x 16 chunks, XOR-swizzled
    __shared__ __align__(16) unsigned short Bs[2][128 * 64];    // 2 x 16 KB: 128 rows x 8 chunks, swizzled
    __shared__ float tn_lds[128];

    const int t = threadIdx.x;
    const int m0 = blockIdx.x * 128;     // 32 m-blocks
    const int grp = blockIdx.y;          // 16 n-groups x 8 tiles of 128
    const int wave = t >> 6;
    const int lane = t & 63;
    const int wm = wave >> 1, wn = wave & 1;
    const int col = lane & 31;           // operand row (m or n), and C/D col
    const int half = lane >> 5;          // k-half of operand; C/D row-group

    // ---- prefetch B segment 0 (issue before A-build VALU work) ----
    {
        int n00 = grp * 8 * 128;
        #pragma unroll
        for (int rr = 0; rr < 4; ++rr) {
            int c = t + rr * 256;             // LDS chunk index 0..1023
            int r = c >> 3;
            int p = (c & 7) ^ (r & 7);        // inverse swizzle on global side
            const unsigned short* gb = Be + (size_t)(n00 + r) * KEXP + p * 8;
            __builtin_amdgcn_global_load_lds((const __attribute__((address_space(1))) void*)gb,
                (__attribute__((address_space(3))) void*)(Bs[0] + c * 8), 16, 0, 0);
        }
    }

    // ---- build A (bf16 of test*inv_bw) swizzled in LDS + exact tnorm ----
    {
        int p = t & 15;                       // 16B chunk within row (constant per thread)
        float4 w0 = *(const float4*)(inv_bw + p * 8);
        float4 w1 = *(const float4*)(inv_bw + p * 8 + 4);
        #pragma unroll
        for (int rr = 0; rr < 8; ++rr) {
            int row = (t >> 4) + rr * 16;
            const float* src = test + (size_t)(m0 + row) * DIM + p * 8;
            float4 v0 = *(const float4*)(src);
            float4 v1 = *(const float4*)(src + 4);
            v0.x *= w0.x; v0.y *= w0.y; v0.z *= w0.z; v0.w *= w0.w;
            v1.x *= w1.x; v1.y *= w1.y; v1.z *= w1.z; v1.w *= w1.w;
            short8 hv;
            hv[0] = (short)f32_to_bf16_rne(v0.x); hv[1] = (short)f32_to_bf16_rne(v0.y);
            hv[2] = (short)f32_to_bf16_rne(v0.z); hv[3] = (short)f32_to_bf16_rne(v0.w);
            hv[4] = (short)f32_to_bf16_rne(v1.x); hv[5] = (short)f32_to_bf16_rne(v1.y);
            hv[6] = (short)f32_to_bf16_rne(v1.z); hv[7] = (short)f32_to_bf16_rne(v1.w);
            int pp = p ^ (row & 7);           // preserves bit 3
            *(short8*)(As + row * 128 + pp * 8) = hv;
            float nv = v0.x*v0.x + v0.y*v0.y + v0.z*v0.z + v0.w*v0.w
                     + v1.x*v1.x + v1.y*v1.y + v1.z*v1.z + v1.w*v1.w;
            #pragma unroll
            for (int off = 1; off < 16; off <<= 1) nv += __shfl_xor(nv, off, 16);
            if ((t & 15) == 0) tn_lds[row] = nv;
        }
    }
    __syncthreads();   // A + tnorm built, B0 staged (vmcnt drain)

    const float scale = scalars[0];

    // per-lane constants
    int abase[2], arx[2];
    #pragma unroll
    for (int tm = 0; tm < 2; ++tm) {
        int rA = wm * 64 + tm * 32 + col;
        abase[tm] = rA * 128;
        arx[tm] = rA & 7;
    }
    int bbase[2], brx[2];
    #pragma unroll
    for (int tn = 0; tn < 2; ++tn) {
        int rB = wn * 64 + tn * 32 + col;
        bbase[tn] = rB * 64;
        brx[tn] = rB & 7;
    }
    float tnv[2][16], rs[2][16];
    #pragma unroll
    for (int tm = 0; tm < 2; ++tm)
        #pragma unroll
        for (int g = 0; g < 16; ++g) {
            int rowi = (g & 3) + 8 * (g >> 2) + 4 * half;
            tnv[tm][g] = tn_lds[wm * 64 + tm * 32 + rowi];
            rs[tm][g] = 0.f;
        }

    float16v acc[2][2];
    float rnv[2];

    // ---- 16 segments: 8 n-tiles x 2 K-chunks (KC=64) ----
    for (int s = 0; s < 16; ++s) {
        int buf = s & 1;
        if (s < 15) {   // prefetch next segment into other buffer
            int j2 = (s + 1) >> 1;
            int kc2 = ((s + 1) & 1) * 64;
            int n0j = (grp * 8 + j2) * 128;
            #pragma unroll
            for (int rr = 0; rr < 4; ++rr) {
                int c = t + rr * 256;
                int r = c >> 3;
                int p = (c & 7) ^ (r & 7);
                const unsigned short* gb = Be + (size_t)(n0j + r) * KEXP + kc2 + p * 8;
                __builtin_amdgcn_global_load_lds((const __attribute__((address_space(1))) void*)gb,
                    (__attribute__((address_space(3))) void*)(Bs[buf ^ 1] + c * 8), 16, 0, 0);
            }
        }
        if ((s & 1) == 0) {   // new n-tile: rnorm + zero acc
            int n0j = (grp * 8 + (s >> 1)) * 128;
            #pragma unroll
            for (int tn = 0; tn < 2; ++tn)
                rnv[tn] = rnorm[n0j + wn * 64 + tn * 32 + col];
            #pragma unroll
            for (int i = 0; i < 2; ++i)
                #pragma unroll
                for (int j = 0; j < 2; ++j)
                    acc[i][j] = (float16v)(0.f);
        }
        #pragma unroll
        for (int ks = 0; ks < 4; ++ks) {
            int kta = (s & 1) * 4 + ks;       // A k-chunk-pair index (global K)
            short8 af[2], bfv[2];
            #pragma unroll
            for (int tm = 0; tm < 2; ++tm)
                af[tm] = *(const short8*)(As + abase[tm] + (((kta * 2 + half) ^ arx[tm]) << 3));
            #pragma unroll
            for (int tn = 0; tn < 2; ++tn)
                bfv[tn] = *(const short8*)(Bs[buf] + bbase[tn] + (((ks * 2 + half) ^ brx[tn]) << 3));
            #pragma unroll
            for (int tm = 0; tm < 2; ++tm)
                #pragma unroll
                for (int tn = 0; tn < 2; ++tn)
                    acc[tm][tn] = __builtin_amdgcn_mfma_f32_32x32x16_bf16(af[tm], bfv[tn], acc[tm][tn], 0, 0, 0);
        }
        if ((s & 1) == 1) {   // n-tile done: exp epilogue into register rowsums
            #pragma unroll
            for (int tm = 0; tm < 2; ++tm)
                #pragma unroll
                for (int g = 0; g < 16; ++g) {
                    float c0 = tnv[tm][g];
                    float sum = 0.f;
                    #pragma unroll
                    for (int tn = 0; tn < 2; ++tn) {
                        float sq = fmaxf(c0 + rnv[tn] - 2.0f * acc[tm][tn][g], 0.0f);
                        sum += __expf(fmaf(scale, sq, -1.0f));
                    }
                    rs[tm][g] += sum;
                }
        }
        __syncthreads();
    }

    // ---- final: reduce across 32 cols + atomics ----
    #pragma unroll
    for (int tm = 0; tm < 2; ++tm) {
        #pragma unroll
        for (int g = 0; g < 16; ++g) {
            float v = rs[tm][g];
            #pragma unroll
            for (int off = 1; off < 32; off <<= 1)
                v += __shfl_xor(v, off, 64);   // offs 1..16 stay within 32-lane half
            if (col == 0) {
                int rowi = (g & 3) + 8 * (g >> 2) + 4 * half;
                atomicAdd(&out[m0 + wm * 64 + tm * 32 + rowi], v);
            }
        }
    }
}

extern "C" void kernel_launch(void* const* d_in, const int* in_sizes, int n_in,
                              void* d_out, int out_size, void* d_ws, size_t ws_size,
                              hipStream_t stream) {
    const float* test  = (const float*)d_in[0];
    const float* train = (const float*)d_in[1];
    float* out = (float*)d_out;

    char* ws = (char*)d_ws;
    unsigned short* Be = (unsigned short*)ws;            // 16384*128*2 = 4,194,304 B
    float* fws    = (float*)(ws + 4194304);
    float* rnorm  = fws;                 // 16384
    float* psum   = rnorm + NTRAIN;      // 16384
    float* psumsq = psum + 16384;        // 16384
    float* inv_bw = psumsq + 16384;      // 128
    float* scalars = inv_bw + 128;       // 8

    hipLaunchKernelGGL(col_stats_partial, dim3(128), dim3(256), 0, stream, train, psum, psumsq, out);
    hipLaunchKernelGGL(bandwidth_kernel, dim3(1), dim3(256), 0, stream, psum, psumsq, inv_bw, scalars);
    hipLaunchKernelGGL(expand_train, dim3(NTRAIN / 2), dim3(256), 0, stream,
                       train, inv_bw, Be, rnorm);
    hipLaunchKernelGGL(kde_main, dim3(NTEST / 128, 16), dim3(256), 0, stream,
                       test, Be, inv_bw, rnorm, scalars, out);
}